// Round 2
// 456.718 us; speedup vs baseline: 1.2307x; 1.2307x over previous
//
#include <hip/hip_runtime.h>
#include <hip/hip_bf16.h>
#include <math.h>

// ---------------------------------------------------------------------------
// GauntTensorProduct: LMAX=4, C=128, COUT=128, NLM=25, B=16384
//   G[i,i1,i2] = sum_{g,h} wq[g] Y[i,g,h] Y[i1,g,h] Y[i2,g,h]   (25^3, exact)
//       -> device prologue (k_nodes -> k_ylm -> k_gaunt), as in the verified
//          R3 kernel. NO host memcpy (graph-capture tripwire).
//   One fused kernel per 4-b tile:
//     M[b,i,i1]   = sum_i2 G[i,i1,i2] sh[b,i2] w2[l(i2)]       (LDS, fp32)
//     feat[j,b,c] = sum_i1 img[b,c,i1] M[b,i,i1]               (LDS, bf16)
//     out[b,128 l^2 + a(2l+1)+j] = sum_c feat[j,b,c] wcT[l,a,c] (MFMA)
//   MFMA A-rows pack 4 j-planes x 4 b (A-row = 4*jj + b_local; A-row of a
//   lane is lane&15, D-row is quad*4+reg -> store j = jb+quad, b = btile+rg).
//   Partial tail groups mask stores (MFMA output rows are independent).
//   feat LDS pitch = 144 u16 (288B) -> conflict-free ds_read_b128.
// ---------------------------------------------------------------------------

typedef __attribute__((ext_vector_type(8))) short bf16x8;
typedef __attribute__((ext_vector_type(4))) float f32x4;
typedef unsigned short u16;

__constant__ int LTAB[25] = {0, 1,1,1, 2,2,2,2,2, 3,3,3,3,3,3,3, 4,4,4,4,4,4,4,4,4};
__constant__ double FACT[9] = {1.0,1.0,2.0,6.0,24.0,120.0,720.0,5040.0,40320.0};

#define PI_D 3.14159265358979323846

__device__ inline u16 f2bf(float x) {
    __hip_bfloat16 h = __float2bfloat16(x);
    return *reinterpret_cast<u16*>(&h);
}

// --- K0: 16-point Gauss-Legendre nodes + (weights * 2pi/15) in double -------
__global__ void k_nodes(double* __restrict__ XG, double* __restrict__ WG) {
    int g = threadIdx.x;
    if (g >= 16) return;
    double x = cos(PI_D * (g + 0.75) / 16.5);
    for (int it = 0; it < 40; ++it) {
        double p0 = 1.0, p1 = x;
        for (int k = 2; k <= 16; ++k) {
            double pk = ((2.0 * k - 1.0) * x * p1 - (k - 1.0) * p0) / k;
            p0 = p1; p1 = pk;
        }
        double dp = 16.0 * (x * p1 - p0) / (x * x - 1.0);
        x -= p1 / dp;
    }
    double p0 = 1.0, p1 = x;
    for (int k = 2; k <= 16; ++k) {
        double pk = ((2.0 * k - 1.0) * x * p1 - (k - 1.0) * p0) / k;
        p0 = p1; p1 = pk;
    }
    double dp = 16.0 * (x * p1 - p0) / (x * x - 1.0);
    XG[g] = x;
    WG[g] = 2.0 / ((1.0 - x * x) * dp * dp) * (2.0 * PI_D / 15.0);
}

// --- K1: real spherical harmonics on the grid, Y[i][g][h] -------------------
__global__ void k_ylm(const double* __restrict__ XG, float* __restrict__ Y) {
    int i = blockIdx.x;
    int t = threadIdx.x;
    if (t >= 240) return;
    int g = t / 15, h = t % 15;
    int l = LTAB[i];
    int m = i - l * l - l;
    int am = m < 0 ? -m : m;
    double x = XG[g];
    double s = sqrt(fmax(0.0, 1.0 - x * x));
    double P[5][5];
    P[0][0] = 1.0;
    for (int mm = 1; mm <= 4; ++mm) P[mm][mm] = -(2.0 * mm - 1.0) * s * P[mm - 1][mm - 1];
    for (int mm = 0; mm < 4; ++mm)  P[mm + 1][mm] = (2.0 * mm + 1.0) * x * P[mm][mm];
    for (int mm = 0; mm <= 4; ++mm)
        for (int ll = mm + 2; ll <= 4; ++ll)
            P[ll][mm] = ((2.0 * ll - 1.0) * x * P[ll - 1][mm] - (ll + mm - 1.0) * P[ll - 2][mm]) / (ll - mm);
    double K = sqrt((2.0 * l + 1.0) / (4.0 * PI_D) * FACT[l - am] / FACT[l + am]);
    double alpha = 2.0 * PI_D * h / 15.0;
    double v;
    if (m == 0)      v = K * P[l][0];
    else if (m > 0)  v = sqrt(2.0) * K * P[l][am] * cos(am * alpha);
    else             v = sqrt(2.0) * K * P[l][am] * sin(am * alpha);
    Y[i * 240 + g * 15 + h] = (float)v;
}

// --- K2: Gaunt tensor G[i][i1][i2] ------------------------------------------
__global__ void k_gaunt(const float* __restrict__ Y, const double* __restrict__ WG,
                        float* __restrict__ G) {
    int t = blockIdx.x * 256 + threadIdx.x;
    if (t >= 15625) return;
    int i  = t / 625;
    int r  = t % 625;
    int i1 = r / 25;
    int i2 = r % 25;
    const float* y0 = Y + i  * 240;
    const float* y1 = Y + i1 * 240;
    const float* y2 = Y + i2 * 240;
    double acc = 0.0;
    for (int g = 0; g < 16; ++g) {
        double shs = 0.0;
        for (int h = 0; h < 15; ++h) {
            int o = g * 15 + h;
            shs += (double)y0[o] * (double)y1[o] * (double)y2[o];
        }
        acc += WG[g] * shs;
    }
    G[t] = (float)acc;
}

// --- K2b: transpose wc -> wcT bf16 [l][a][c] --------------------------------
__global__ void k_wcT(const float* __restrict__ wc, u16* __restrict__ wcT) {
    int idx = blockIdx.x * 256 + threadIdx.x;   // 81920 total
    if (idx >= 81920) return;
    int l = idx >> 14;
    int r = idx & 16383;
    int c = r >> 7;
    int a = r & 127;
    wcT[(l << 14) + (a << 7) + c] = f2bf(wc[idx]);
}

// --- per-l tail of the fused kernel -----------------------------------------
template<int L>
__device__ __forceinline__ void do_l(int wave, int lane, int btile,
                                     const float (&img0)[25], const float (&img1)[25],
                                     const float (*Ms)[704],
                                     u16 (*featLDS)[4][144],
                                     const u16* __restrict__ wcT,
                                     float* __restrict__ out)
{
    constexpr int D = 2 * L + 1;
    int col = lane & 15, quad = lane >> 4;

    // W fragments (L2-resident), issued early to overlap with plane compute.
    const u16* wl = wcT + (L << 14);
    bf16x8 Wf[2][4];
#pragma unroll
    for (int t = 0; t < 2; ++t) {
        int a = ((wave * 2 + t) << 4) + col;
#pragma unroll
        for (int ks = 0; ks < 4; ++ks)
            Wf[t][ks] = *(const bf16x8*)&wl[a * 128 + ks * 32 + (quad << 3)];
    }

    // feat planes for this l -> LDS (bf16). wave == b_local; 2 c per lane.
#pragma unroll
    for (int j = 0; j < D; ++j) {
        int i = L * L + j;
        const float* mr = &Ms[wave][i * 28];
        float a0 = 0.0f, a1 = 0.0f;
#pragma unroll
        for (int q = 0; q < 6; ++q) {
            float4 m4 = *(const float4*)&mr[q * 4];
            a0 = fmaf(img0[q*4+0], m4.x, a0);  a1 = fmaf(img1[q*4+0], m4.x, a1);
            a0 = fmaf(img0[q*4+1], m4.y, a0);  a1 = fmaf(img1[q*4+1], m4.y, a1);
            a0 = fmaf(img0[q*4+2], m4.z, a0);  a1 = fmaf(img1[q*4+2], m4.z, a1);
            a0 = fmaf(img0[q*4+3], m4.w, a0);  a1 = fmaf(img1[q*4+3], m4.w, a1);
        }
        float ml = mr[24];
        a0 = fmaf(img0[24], ml, a0);  a1 = fmaf(img1[24], ml, a1);
        featLDS[j][wave][lane]      = f2bf(a0);
        featLDS[j][wave][lane + 64] = f2bf(a1);
    }
    __syncthreads();

    // MFMA: A-row = 4*jj + b_local. Lane reads plane jb + (col>>2), b = col&3.
#pragma unroll
    for (int jb = 0; jb < D; jb += 4) {
        int nj = D - jb; if (nj > 4) nj = 4;
        const u16* arow = &featLDS[jb + (col >> 2)][col & 3][quad << 3];
        f32x4 acc0 = (f32x4){0.f, 0.f, 0.f, 0.f};
        f32x4 acc1 = (f32x4){0.f, 0.f, 0.f, 0.f};
#pragma unroll
        for (int ks = 0; ks < 4; ++ks) {
            bf16x8 Af = *(const bf16x8*)&arow[ks * 32];
            acc0 = __builtin_amdgcn_mfma_f32_16x16x32_bf16(Af, Wf[0][ks], acc0, 0, 0, 0);
            acc1 = __builtin_amdgcn_mfma_f32_16x16x32_bf16(Af, Wf[1][ks], acc1, 0, 0, 0);
        }
        // D-row r = quad*4 + rg = 4*jj + b_local  =>  j = jb+quad, b = btile+rg
        if (quad < nj) {
            int j = jb + quad;
#pragma unroll
            for (int t = 0; t < 2; ++t) {
                int a = ((wave * 2 + t) << 4) + col;
                const f32x4& ac = t ? acc1 : acc0;
#pragma unroll
                for (int rg = 0; rg < 4; ++rg)
                    out[(size_t)(btile + rg) * 3200 + 128 * L * L + a * D + j] = ac[rg];
            }
        }
    }
    __syncthreads();   // featLDS reuse hazard for next l
}

// --- the fused kernel: M + feat + out-GEMM, 4 b-rows per block --------------
__global__ __launch_bounds__(256, 2) void k_fused(
        const float* __restrict__ feature, const float* __restrict__ sh,
        const float* __restrict__ w1, const float* __restrict__ w2,
        const float* __restrict__ G, const u16* __restrict__ wcT,
        float* __restrict__ out)
{
    __shared__ alignas(16) u16   featLDS[12][4][144];   // 13.8 KB
    __shared__ alignas(16) float Ms[4][704];            // 11.3 KB (pitch 28)
    __shared__ float kerns[4][25];

    int tid = threadIdx.x;
    int wave = tid >> 6, lane = tid & 63;
    int btile = blockIdx.x << 2;

    if (tid < 100) {
        int nb = tid / 25, i2 = tid - nb * 25;
        kerns[nb][i2] = sh[(size_t)(btile + nb) * 25 + i2] * w2[LTAB[i2]];
    }

    // img (per-wave b, 2 c per lane) — independent global loads, issued early
    int b = btile + wave;
    const float* frow = feature + (size_t)b * 3200;
    int c0 = lane, c1 = lane + 64;
    float img0[25], img1[25];
    {
        float wa = w1[c0 * 5 + 0], wb_ = w1[c1 * 5 + 0];
        img0[0] = frow[c0] * wa;  img1[0] = frow[c1] * wb_;
        wa = w1[c0 * 5 + 1]; wb_ = w1[c1 * 5 + 1];
#pragma unroll
        for (int j = 0; j < 3; ++j) { img0[1+j] = frow[128 + c0*3 + j] * wa;
                                      img1[1+j] = frow[128 + c1*3 + j] * wb_; }
        wa = w1[c0 * 5 + 2]; wb_ = w1[c1 * 5 + 2];
#pragma unroll
        for (int j = 0; j < 5; ++j) { img0[4+j] = frow[512 + c0*5 + j] * wa;
                                      img1[4+j] = frow[512 + c1*5 + j] * wb_; }
        wa = w1[c0 * 5 + 3]; wb_ = w1[c1 * 5 + 3];
#pragma unroll
        for (int j = 0; j < 7; ++j) { img0[9+j] = frow[1152 + c0*7 + j] * wa;
                                      img1[9+j] = frow[1152 + c1*7 + j] * wb_; }
        wa = w1[c0 * 5 + 4]; wb_ = w1[c1 * 5 + 4];
#pragma unroll
        for (int j = 0; j < 9; ++j) { img0[16+j] = frow[2048 + c0*9 + j] * wa;
                                      img1[16+j] = frow[2048 + c1*9 + j] * wb_; }
    }

    __syncthreads();   // kerns ready

    // M[4][625] in LDS: thread <-> row r; G rows come from L2 (62.5 KB resident)
    for (int r = tid; r < 625; r += 256) {
        const float* gr = G + r * 25;
        float a0 = 0.f, a1 = 0.f, a2 = 0.f, a3 = 0.f;
#pragma unroll
        for (int i2 = 0; i2 < 25; ++i2) {
            float gv = gr[i2];
            a0 = fmaf(gv, kerns[0][i2], a0);
            a1 = fmaf(gv, kerns[1][i2], a1);
            a2 = fmaf(gv, kerns[2][i2], a2);
            a3 = fmaf(gv, kerns[3][i2], a3);
        }
        int i = r / 25, i1 = r - i * 25;
        int o = i * 28 + i1;
        Ms[0][o] = a0; Ms[1][o] = a1; Ms[2][o] = a2; Ms[3][o] = a3;
    }
    __syncthreads();   // Ms ready

    do_l<0>(wave, lane, btile, img0, img1, Ms, featLDS, wcT, out);
    do_l<1>(wave, lane, btile, img0, img1, Ms, featLDS, wcT, out);
    do_l<2>(wave, lane, btile, img0, img1, Ms, featLDS, wcT, out);
    do_l<3>(wave, lane, btile, img0, img1, Ms, featLDS, wcT, out);
    do_l<4>(wave, lane, btile, img0, img1, Ms, featLDS, wcT, out);
}

extern "C" void kernel_launch(void* const* d_in, const int* in_sizes, int n_in,
                              void* d_out, int out_size, void* d_ws, size_t ws_size,
                              hipStream_t stream) {
    const float* feature = (const float*)d_in[0];   // (16384, 3200)
    const float* sh      = (const float*)d_in[1];   // (16384, 25)
    const float* w1      = (const float*)d_in[2];   // (128, 5)
    const float* w2      = (const float*)d_in[3];   // (5,)
    const float* wc      = (const float*)d_in[4];   // (5, 128, 128)
    float* out = (float*)d_out;                     // (16384, 3200)

    char* w = (char*)d_ws;
    double* XG  = (double*)(w + 0);                  // 16 d
    double* WG  = (double*)(w + 128);                // 16 d
    float*  Yf  = (float*)(w + 256);                 // 6000 f
    float*  Gf  = (float*)(w + 24320);               // 15625 f
    u16*    WcT = (u16*)(w + 87040);                 // 81920 u16

    hipLaunchKernelGGL(k_nodes, dim3(1),    dim3(64),  0, stream, XG, WG);
    hipLaunchKernelGGL(k_ylm,   dim3(25),   dim3(256), 0, stream, XG, Yf);
    hipLaunchKernelGGL(k_gaunt, dim3(62),   dim3(256), 0, stream, Yf, WG, Gf);
    hipLaunchKernelGGL(k_wcT,   dim3(320),  dim3(256), 0, stream, wc, WcT);
    hipLaunchKernelGGL(k_fused, dim3(4096), dim3(256), 0, stream,
                       feature, sh, w1, w2, Gf, WcT, out);
}